// Round 2
// baseline (450.573 us; speedup 1.0000x reference)
//
#include <hip/hip_runtime.h>
#include <hip/hip_bf16.h>
#include <stdint.h>

#define NDIM 4096

typedef __attribute__((ext_vector_type(8))) __bf16 bf16x8;
typedef __attribute__((ext_vector_type(4))) float f32x4;

__device__ inline void g2lds16(const void* g, void* l) {
  __builtin_amdgcn_global_load_lds(
      (const __attribute__((address_space(1))) void*)g,
      (__attribute__((address_space(3))) void*)l, 16, 0, 0);
}

__device__ inline unsigned short f2bf(float f) {
  union { float f; uint32_t u; } c; c.f = f;
  uint32_t u = c.u;
  uint32_t r = ((u >> 16) & 1u) + 0x7FFFu;
  return (unsigned short)((u + r) >> 16);
}

__device__ inline float bf2f(ushort u) {
  union { uint32_t u; float f; } c; c.u = ((uint32_t)u) << 16;
  return c.f;
}

// ---------------- fp32 -> bf16 convert (vectorized) ----------------
__global__ __launch_bounds__(256) void convert_kernel(const float* __restrict__ in,
                                                      ushort* __restrict__ out) {
  int idx = blockIdx.x * 256 + threadIdx.x;
  float4 v = ((const float4*)in)[idx];
  ushort4 o;
  o.x = f2bf(v.x); o.y = f2bf(v.y); o.z = f2bf(v.z); o.w = f2bf(v.w);
  ((ushort4*)out)[idx] = o;
}

// ---------------- big GEMM: q = A @ B^T + bias  (bf16 MFMA, 256^2 tile) ------
// A = data_q bf16, B = W_q bf16, both [4096][4096] row-major.
// q[i,j] = sum_k A[i,k]*B[j,k] + bias[j], bf16 out.
// 512 threads = 8 waves (2Mx4N), per-wave output 128x64, BK=64.
// LDS: 2-deep double buffer, XOR-swizzled (slot ^= row&7), counted vmcnt(8).

__device__ inline bf16x8 ldfrag(const ushort* buf, int row, int kk, int lg) {
  int idx = (row * 64 + kk * 32 + lg * 8) ^ ((row & 7) << 3);
  return *(const bf16x8*)&buf[idx];
}

__global__ __launch_bounds__(512, 2) void gemm_q_kernel(const ushort* __restrict__ Abf,
                                                        const ushort* __restrict__ Bbf,
                                                        const float* __restrict__ bias,
                                                        ushort* __restrict__ qout) {
  __shared__ __align__(16) ushort As[2][16384];  // [buf][256*64]
  __shared__ __align__(16) ushort Bs[2][16384];

  const int tid = threadIdx.x;
  // XCD swizzle: 256 wgs, 8 XCDs, 32 per XCD (bijective)
  const int wg = blockIdx.x;
  const int swz = (wg & 7) * 32 + (wg >> 3);
  const int i0 = (swz >> 4) * 256;
  const int j0 = (swz & 15) * 256;

  const int lane = tid & 63, wid = tid >> 6;
  const int wr = wid >> 2, wc = wid & 3;           // 2 x 4 wave grid
  const int l15 = lane & 15, lg = lane >> 4;

  // staging map: issue i covers rows i*64..i*64+63; 8 threads per 128B row
  const int srow = tid >> 3;                       // 0..63
  const int scol = ((tid & 7) ^ (srow & 7)) * 8;   // pre-swizzled global slot

#define STAGE(tensor, r0, k0v, buf)                                          \
  {                                                                          \
    _Pragma("unroll")                                                        \
    for (int i_ = 0; i_ < 4; ++i_) {                                         \
      g2lds16(tensor + (size_t)((r0) + i_ * 64 + srow) * NDIM + (k0v) + scol,\
              (void*)&buf[i_ * 4096 + tid * 8]);                             \
    }                                                                        \
  }

  f32x4 acc[8][4] = {};

  // prologue: stage kt=0 -> buf0, kt=1 -> buf1
  STAGE(Abf, i0, 0, As[0]);
  STAGE(Bbf, j0, 0, Bs[0]);
  STAGE(Abf, i0, 64, As[1]);
  STAGE(Bbf, j0, 64, Bs[1]);
  asm volatile("s_waitcnt vmcnt(8)" ::: "memory");  // kt0 complete, kt1 in flight
  __builtin_amdgcn_sched_barrier(0);
  __builtin_amdgcn_s_barrier();
  __builtin_amdgcn_sched_barrier(0);

  for (int kt = 0; kt < 64; ++kt) {
    const int cur = kt & 1;
    const ushort* A = As[cur];
    const ushort* B = Bs[cur];

    bf16x8 a0[4][2], a1[4][2], bfr[4][2];
#pragma unroll
    for (int m = 0; m < 4; ++m)
#pragma unroll
      for (int kk = 0; kk < 2; ++kk)
        a0[m][kk] = ldfrag(A, wr * 128 + m * 16 + l15, kk, lg);
#pragma unroll
    for (int n = 0; n < 4; ++n)
#pragma unroll
      for (int kk = 0; kk < 2; ++kk)
        bfr[n][kk] = ldfrag(B, wc * 64 + n * 16 + l15, kk, lg);
#pragma unroll
    for (int m = 0; m < 4; ++m)
#pragma unroll
      for (int kk = 0; kk < 2; ++kk)
        a1[m][kk] = ldfrag(A, wr * 128 + 64 + m * 16 + l15, kk, lg);

    // MFMA half-cluster 0 (rows wr*128 .. +63)
    __builtin_amdgcn_s_setprio(1);
#pragma unroll
    for (int kk = 0; kk < 2; ++kk)
#pragma unroll
      for (int m = 0; m < 4; ++m)
#pragma unroll
        for (int n = 0; n < 4; ++n)
          acc[m][n] = __builtin_amdgcn_mfma_f32_16x16x32_bf16(a0[m][kk], bfr[n][kk], acc[m][n], 0, 0, 0);
    __builtin_amdgcn_s_setprio(0);

    // all of buf[cur]'s LDS reads are issued; drain them, then join waves
    asm volatile("s_waitcnt lgkmcnt(0)" ::: "memory");
    __builtin_amdgcn_sched_barrier(0);
    __builtin_amdgcn_s_barrier();
    __builtin_amdgcn_sched_barrier(0);

    // safe to overwrite buf[cur]: stage kt+2 (overlaps with MFMA half 1)
    const int knext = ((kt + 2) & 63) * 64;
    STAGE(Abf, i0, knext, As[cur]);
    STAGE(Bbf, j0, knext, Bs[cur]);

    // MFMA half-cluster 1 (rows wr*128+64 .. +127)
    __builtin_amdgcn_s_setprio(1);
#pragma unroll
    for (int kk = 0; kk < 2; ++kk)
#pragma unroll
      for (int m = 0; m < 4; ++m)
#pragma unroll
        for (int n = 0; n < 4; ++n)
          acc[m + 4][n] = __builtin_amdgcn_mfma_f32_16x16x32_bf16(a1[m][kk], bfr[n][kk], acc[m + 4][n], 0, 0, 0);
    __builtin_amdgcn_s_setprio(0);

    // counted wait: retire kt+1's 8 loads, keep kt+2's 8 in flight
    asm volatile("s_waitcnt vmcnt(8)" ::: "memory");
    __builtin_amdgcn_sched_barrier(0);
    __builtin_amdgcn_s_barrier();
    __builtin_amdgcn_sched_barrier(0);
  }

  // epilogue: C row = wr*128 + m*16 + lg*4 + r, col = wc*64 + n*16 + l15
  float bv[4];
#pragma unroll
  for (int n = 0; n < 4; ++n) bv[n] = bias[j0 + wc * 64 + n * 16 + l15];
#pragma unroll
  for (int m = 0; m < 8; ++m) {
    const int row = i0 + wr * 128 + m * 16 + lg * 4;
#pragma unroll
    for (int n = 0; n < 4; ++n) {
      const int col = j0 + wc * 64 + n * 16 + l15;
#pragma unroll
      for (int r = 0; r < 4; ++r)
        qout[(size_t)(row + r) * NDIM + col] = f2bf(acc[m][n][r] + bv[n]);
    }
  }
#undef STAGE
}

// ---------------- k = data_k @ W_k^T + b_k  -> k_out[j][m], [6][4096] -------
__global__ __launch_bounds__(256) void gemv_k_kernel(const float* __restrict__ data_k,
                                                     const float* __restrict__ W_k,
                                                     const float* __restrict__ b_k,
                                                     float* __restrict__ k_out) {
  const int wave = threadIdx.x >> 6, lane = threadIdx.x & 63;
  const int m = blockIdx.x * 4 + wave;  // grid 1024 -> m in [0,4096)
  const float4* W = (const float4*)(W_k + (size_t)m * NDIM);
  const float4* D = (const float4*)data_k;
  float acc[6] = {0.f, 0.f, 0.f, 0.f, 0.f, 0.f};
  for (int it = lane; it < NDIM / 4; it += 64) {
    float4 w = W[it];
#pragma unroll
    for (int j = 0; j < 6; ++j) {
      float4 d = D[j * (NDIM / 4) + it];
      acc[j] += w.x * d.x + w.y * d.y + w.z * d.z + w.w * d.w;
    }
  }
#pragma unroll
  for (int j = 0; j < 6; ++j)
#pragma unroll
    for (int off = 1; off < 64; off <<= 1) acc[j] += __shfl_xor(acc[j], off);
  if (lane == 0) {
    const float bv = b_k[m];
#pragma unroll
    for (int j = 0; j < 6; ++j) k_out[j * NDIM + m] = acc[j] + bv;
  }
}

// ---------------- new_q^T partials: newq_t[j][m] += sum_n q[n,m]*W_lin[j,n] --
__global__ __launch_bounds__(256) void newq_kernel(const ushort* __restrict__ q,
                                                   const float* __restrict__ W_lin,
                                                   float* __restrict__ newq_t) {
  const int m = blockIdx.x * 256 + threadIdx.x;  // grid.x = 16
  const int n0 = blockIdx.y * 128;               // grid.y = 32
  float acc[6] = {0.f, 0.f, 0.f, 0.f, 0.f, 0.f};
  for (int n = n0; n < n0 + 128; ++n) {
    const float qv = bf2f(q[(size_t)n * NDIM + m]);
#pragma unroll
    for (int j = 0; j < 6; ++j) acc[j] += qv * W_lin[j * NDIM + n];
  }
#pragma unroll
  for (int j = 0; j < 6; ++j) atomicAdd(&newq_t[j * NDIM + m], acc[j]);
}

// ---------------- k_mod = relu6(k^2 + 2k + (newq_t + b_lin)*(1+|k|)) --------
__global__ __launch_bounds__(256) void kmod_kernel(const float* __restrict__ k_in,
                                                   const float* __restrict__ newq_t,
                                                   const float* __restrict__ b_lin,
                                                   float* __restrict__ k_mod) {
  const int idx = blockIdx.x * 256 + threadIdx.x;  // 0..24575
  const int j = idx >> 12;
  const float kv = k_in[idx];
  const float ctx = newq_t[idx] + b_lin[j];
  float v = kv * kv + 2.f * kv + ctx * (1.f + fabsf(kv));
  v = fminf(fmaxf(v, 0.f), 6.f);
  k_mod[idx] = v;
}

// ---------------- out[n][j] = (sum_m q[n,m]*k_mod[j,m]) / 64 ----------------
__global__ __launch_bounds__(256) void dot_kernel(const ushort* __restrict__ q,
                                                  const float* __restrict__ k_mod,
                                                  float* __restrict__ out) {
  const int wave = threadIdx.x >> 6, lane = threadIdx.x & 63;
  const int n = blockIdx.x * 4 + wave;  // grid 1024
  const uint4* Q = (const uint4*)(q + (size_t)n * NDIM);  // 512 x 16B (8 bf16)
  float acc[6] = {0.f, 0.f, 0.f, 0.f, 0.f, 0.f};
  for (int it = lane; it < 512; it += 64) {
    uint4 v = Q[it];
    float qf[8];
    qf[0] = __builtin_bit_cast(float, v.x << 16);
    qf[1] = __builtin_bit_cast(float, v.x & 0xffff0000u);
    qf[2] = __builtin_bit_cast(float, v.y << 16);
    qf[3] = __builtin_bit_cast(float, v.y & 0xffff0000u);
    qf[4] = __builtin_bit_cast(float, v.z << 16);
    qf[5] = __builtin_bit_cast(float, v.z & 0xffff0000u);
    qf[6] = __builtin_bit_cast(float, v.w << 16);
    qf[7] = __builtin_bit_cast(float, v.w & 0xffff0000u);
#pragma unroll
    for (int j = 0; j < 6; ++j) {
      const float4* KM = (const float4*)(k_mod + j * NDIM);
      float4 k0 = KM[it * 2], k1 = KM[it * 2 + 1];
      acc[j] += qf[0] * k0.x + qf[1] * k0.y + qf[2] * k0.z + qf[3] * k0.w
              + qf[4] * k1.x + qf[5] * k1.y + qf[6] * k1.z + qf[7] * k1.w;
    }
  }
#pragma unroll
  for (int j = 0; j < 6; ++j)
#pragma unroll
    for (int off = 1; off < 64; off <<= 1) acc[j] += __shfl_xor(acc[j], off);
  if (lane == 0) {
#pragma unroll
    for (int j = 0; j < 6; ++j) out[n * 6 + j] = acc[j] * 0.015625f;  // /sqrt(4096)
  }
}

extern "C" void kernel_launch(void* const* d_in, const int* in_sizes, int n_in,
                              void* d_out, int out_size, void* d_ws, size_t ws_size,
                              hipStream_t stream) {
  const float* data_q = (const float*)d_in[0];
  const float* data_k = (const float*)d_in[1];
  const float* W_q    = (const float*)d_in[2];
  const float* b_q    = (const float*)d_in[3];
  const float* W_lin  = (const float*)d_in[4];
  const float* b_lin  = (const float*)d_in[5];
  const float* W_k    = (const float*)d_in[6];
  const float* b_k    = (const float*)d_in[7];
  float* out = (float*)d_out;

  char* ws = (char*)d_ws;
  ushort* Abf   = (ushort*)ws;                          // 32 MB
  ushort* Bbf   = (ushort*)(ws + ((size_t)32 << 20));   // 32 MB
  ushort* q_bf  = (ushort*)(ws + ((size_t)64 << 20));   // 32 MB (bf16 q)
  float*  k_arr = (float*)(ws + ((size_t)96 << 20));    // 96 KB
  float*  newq  = k_arr + 6 * NDIM;                     // 96 KB
  float*  kmod  = newq + 6 * NDIM;                      // 96 KB

  hipMemsetAsync(newq, 0, 6 * NDIM * sizeof(float), stream);

  convert_kernel<<<16384, 256, 0, stream>>>(data_q, Abf);
  convert_kernel<<<16384, 256, 0, stream>>>(W_q, Bbf);
  gemm_q_kernel<<<256, 512, 0, stream>>>(Abf, Bbf, b_q, q_bf);
  gemv_k_kernel<<<1024, 256, 0, stream>>>(data_k, W_k, b_k, k_arr);
  newq_kernel<<<dim3(16, 32), 256, 0, stream>>>(q_bf, W_lin, newq);
  kmod_kernel<<<96, 256, 0, stream>>>(k_arr, newq, b_lin, kmod);
  dot_kernel<<<1024, 256, 0, stream>>>(q_bf, kmod, out);
}

// Round 3
// 360.471 us; speedup vs baseline: 1.2500x; 1.2500x over previous
//
#include <hip/hip_runtime.h>
#include <hip/hip_bf16.h>
#include <stdint.h>

#define NDIM 4096

typedef __attribute__((ext_vector_type(8))) __bf16 bf16x8;
typedef __attribute__((ext_vector_type(4))) float f32x4;

__device__ inline void g2lds16(const void* g, void* l) {
  __builtin_amdgcn_global_load_lds(
      (const __attribute__((address_space(1))) void*)g,
      (__attribute__((address_space(3))) void*)l, 16, 0, 0);
}

__device__ inline unsigned short f2bf(float f) {
  union { float f; uint32_t u; } c; c.f = f;
  uint32_t u = c.u;
  uint32_t r = ((u >> 16) & 1u) + 0x7FFFu;
  return (unsigned short)((u + r) >> 16);
}

__device__ inline float bf2f(ushort u) {
  union { uint32_t u; float f; } c; c.u = ((uint32_t)u) << 16;
  return c.f;
}

// ---------------- fused fp32 -> bf16 convert for data_q and W_q -------------
__global__ __launch_bounds__(256) void convert2_kernel(const float* __restrict__ a,
                                                       ushort* __restrict__ oa,
                                                       const float* __restrict__ b,
                                                       ushort* __restrict__ ob) {
  const int bid = blockIdx.x;
  const float* in = (bid < 16384) ? a : b;
  ushort* out = (bid < 16384) ? oa : ob;
  const int idx = (bid & 16383) * 256 + threadIdx.x;
  float4 v = ((const float4*)in)[idx];
  ushort4 o;
  o.x = f2bf(v.x); o.y = f2bf(v.y); o.z = f2bf(v.z); o.w = f2bf(v.w);
  ((ushort4*)out)[idx] = o;
}

// ---------------- big GEMM: q = A @ B^T + bias  (bf16 MFMA, 256^2, 4-phase) --
// A = data_q bf16, B = W_q bf16, both [4096][4096] row-major.
// 512 threads = 8 waves (2M x 4N). Per-wave output = two 64-row blocks x 64 cols.
// LDS: 2-deep double buffer, each K-tile stored as 2 halves (128 rows) per
// tensor, XOR-swizzled. Per K-tile: 4 phases, each {dsr quadrant | stage one
// half-tile | bar | lgkm0 | 16 MFMA | bar}; counted vmcnt(4)@P2, vmcnt(2)@P4.

__device__ inline bf16x8 ldfrag(const ushort* half_buf, int rrow, int blk) {
  int idx = (rrow * 64 + blk * 8) ^ ((rrow & 7) << 3);
  return *(const bf16x8*)&half_buf[idx];
}

__global__ __launch_bounds__(512, 2) void gemm_q_kernel(const ushort* __restrict__ Abf,
                                                        const ushort* __restrict__ Bbf,
                                                        const float* __restrict__ bias,
                                                        ushort* __restrict__ qout) {
  __shared__ __align__(16) ushort As[2][2][8192];  // [buf][half][128*64]
  __shared__ __align__(16) ushort Bs[2][2][8192];

  const int tid = threadIdx.x;
  const int wg = blockIdx.x;
  const int swz = (wg & 7) * 32 + (wg >> 3);   // XCD-bijective (256 wgs)
  const int i0 = (swz >> 4) * 256;
  const int j0 = (swz & 15) * 256;

  const int lane = tid & 63, wid = tid >> 6;
  const int wr = wid >> 2, wc = wid & 3;       // 2 x 4 wave grid
  const int l15 = lane & 15, lg = lane >> 4;

  const int srow = tid >> 3;                    // 0..63
  const int scol = ((tid & 7) ^ (srow & 7)) * 8;  // pre-swizzled global slot

  // stage one 128-row half (16KB) = 2 x global_load_lds per thread
#define STAGE_HALF(tensor, grow0, k0v, dst)                                    \
  {                                                                            \
    g2lds16((tensor) + (size_t)((grow0) + srow) * NDIM + (k0v) + scol,         \
            (void*)&(dst)[tid * 8]);                                           \
    g2lds16((tensor) + (size_t)((grow0) + 64 + srow) * NDIM + (k0v) + scol,    \
            (void*)&(dst)[4096 + tid * 8]);                                    \
  }

#define SB __builtin_amdgcn_sched_barrier(0)
#define BAR { SB; __builtin_amdgcn_s_barrier(); SB; }
#define LGKM0 { asm volatile("s_waitcnt lgkmcnt(0)" ::: "memory"); SB; }

  f32x4 acc[8][4] = {};
  bf16x8 a[4][2];      // A quadrant frags (mi, kk), reloaded per mh-phase
  bf16x8 b[2][2][2];   // B frags (nh, ni, kk), nh0 loaded P1, nh1 loaded P2

  // dsr helpers (compile-time indices via unrolled loops)
#define DSR_A(bufc, mh)                                                        \
  _Pragma("unroll") for (int mi = 0; mi < 4; ++mi)                             \
  _Pragma("unroll") for (int kk = 0; kk < 2; ++kk)                             \
    a[mi][kk] = ldfrag(As[bufc][mh], wr * 64 + mi * 16 + l15, kk * 4 + lg);

#define DSR_B(bufc, nh)                                                        \
  _Pragma("unroll") for (int ni = 0; ni < 2; ++ni)                             \
  _Pragma("unroll") for (int kk = 0; kk < 2; ++kk)                             \
    b[nh][ni][kk] = ldfrag(Bs[bufc][wc >> 1],                                  \
                           (wc & 1) * 64 + ((nh) * 2 + ni) * 16 + l15,         \
                           kk * 4 + lg);

#define MFMA_PH(mh, nh)                                                        \
  __builtin_amdgcn_s_setprio(1);                                              \
  _Pragma("unroll") for (int kk = 0; kk < 2; ++kk)                             \
  _Pragma("unroll") for (int mi = 0; mi < 4; ++mi)                             \
  _Pragma("unroll") for (int ni = 0; ni < 2; ++ni)                             \
    acc[(mh) * 4 + mi][(nh) * 2 + ni] = __builtin_amdgcn_mfma_f32_16x16x32_bf16( \
        a[mi][kk], b[nh][ni][kk], acc[(mh) * 4 + mi][(nh) * 2 + ni], 0, 0, 0); \
  __builtin_amdgcn_s_setprio(0);

  // prologue: tile 0 -> buf 0, order A-h0, B-h0, B-h1, A-h1 (A-h1 may stay in flight)
  STAGE_HALF(Abf, i0 + 0,   0, As[0][0]);
  STAGE_HALF(Bbf, j0 + 0,   0, Bs[0][0]);
  STAGE_HALF(Bbf, j0 + 128, 0, Bs[0][1]);
  STAGE_HALF(Abf, i0 + 128, 0, As[0][1]);
  asm volatile("s_waitcnt vmcnt(2)" ::: "memory");
  BAR;

  for (int kt = 0; kt < 64; ++kt) {
    const int bufc = kt & 1, bufn = bufc ^ 1;
    const int kn1 = ((kt + 1) & 63) * 64;

    // ---- P1: quadrant (mh0, nh0); stage A-h0(kt+1)
    DSR_A(bufc, 0);
    DSR_B(bufc, 0);
    STAGE_HALF(Abf, i0 + 0, kn1, As[bufn][0]);
    BAR; LGKM0;
    MFMA_PH(0, 0);
    BAR;

    // ---- P2: quadrant (mh0, nh1); stage B-h0(kt+1)
    DSR_B(bufc, 1);
    STAGE_HALF(Bbf, j0 + 0, kn1, Bs[bufn][0]);
    BAR; LGKM0;
    MFMA_PH(0, 1);
    asm volatile("s_waitcnt vmcnt(4)" ::: "memory");  // A-h1(kt) resident for P3
    BAR;

    // ---- P3: quadrant (mh1, nh0); stage B-h1(kt+1)
    DSR_A(bufc, 1);
    STAGE_HALF(Bbf, j0 + 128, kn1, Bs[bufn][1]);
    BAR; LGKM0;
    MFMA_PH(1, 0);
    BAR;

    // ---- P4: quadrant (mh1, nh1); stage A-h1(kt+1)
    STAGE_HALF(Abf, i0 + 128, kn1, As[bufn][1]);
    BAR;
    MFMA_PH(1, 1);
    asm volatile("s_waitcnt vmcnt(2)" ::: "memory");  // all of kt+1 except A-h1
    BAR;
  }

  // epilogue: acc[m][n]: row = i0 + (m>>2)*128 + wr*64 + (m&3)*16 + lg*4 + r
  //                      col = j0 + wc*64 + n*16 + l15
  float bv[4];
#pragma unroll
  for (int n = 0; n < 4; ++n) bv[n] = bias[j0 + wc * 64 + n * 16 + l15];
#pragma unroll
  for (int m = 0; m < 8; ++m) {
    const int row = i0 + (m >> 2) * 128 + wr * 64 + (m & 3) * 16 + lg * 4;
#pragma unroll
    for (int n = 0; n < 4; ++n) {
      const int col = j0 + wc * 64 + n * 16 + l15;
#pragma unroll
      for (int r = 0; r < 4; ++r)
        qout[(size_t)(row + r) * NDIM + col] = f2bf(acc[m][n][r] + bv[n]);
    }
  }
#undef STAGE_HALF
#undef DSR_A
#undef DSR_B
#undef MFMA_PH
#undef BAR
#undef LGKM0
#undef SB
}

// ---------------- k = data_k @ W_k^T + b_k  -> k_out[j][m], [6][4096] -------
__global__ __launch_bounds__(256) void gemv_k_kernel(const float* __restrict__ data_k,
                                                     const float* __restrict__ W_k,
                                                     const float* __restrict__ b_k,
                                                     float* __restrict__ k_out) {
  const int wave = threadIdx.x >> 6, lane = threadIdx.x & 63;
  const int m = blockIdx.x * 4 + wave;  // grid 1024 -> m in [0,4096)
  const float4* W = (const float4*)(W_k + (size_t)m * NDIM);
  const float4* D = (const float4*)data_k;
  float acc[6] = {0.f, 0.f, 0.f, 0.f, 0.f, 0.f};
  for (int it = lane; it < NDIM / 4; it += 64) {
    float4 w = W[it];
#pragma unroll
    for (int j = 0; j < 6; ++j) {
      float4 d = D[j * (NDIM / 4) + it];
      acc[j] += w.x * d.x + w.y * d.y + w.z * d.z + w.w * d.w;
    }
  }
#pragma unroll
  for (int j = 0; j < 6; ++j)
#pragma unroll
    for (int off = 1; off < 64; off <<= 1) acc[j] += __shfl_xor(acc[j], off);
  if (lane == 0) {
    const float bv = b_k[m];
#pragma unroll
    for (int j = 0; j < 6; ++j) k_out[j * NDIM + m] = acc[j] + bv;
  }
}

// ---------------- new_q^T partials: newq_t[j][m] += sum_n q[n,m]*W_lin[j,n] --
__global__ __launch_bounds__(256) void newq_kernel(const ushort* __restrict__ q,
                                                   const float* __restrict__ W_lin,
                                                   float* __restrict__ newq_t) {
  const int m = blockIdx.x * 256 + threadIdx.x;  // grid.x = 16
  const int n0 = blockIdx.y * 128;               // grid.y = 32
  float acc[6] = {0.f, 0.f, 0.f, 0.f, 0.f, 0.f};
  for (int n = n0; n < n0 + 128; ++n) {
    const float qv = bf2f(q[(size_t)n * NDIM + m]);
#pragma unroll
    for (int j = 0; j < 6; ++j) acc[j] += qv * W_lin[j * NDIM + n];
  }
#pragma unroll
  for (int j = 0; j < 6; ++j) atomicAdd(&newq_t[j * NDIM + m], acc[j]);
}

// ---------------- k_mod = relu6(k^2 + 2k + (newq_t + b_lin)*(1+|k|)) --------
__global__ __launch_bounds__(256) void kmod_kernel(const float* __restrict__ k_in,
                                                   const float* __restrict__ newq_t,
                                                   const float* __restrict__ b_lin,
                                                   float* __restrict__ k_mod) {
  const int idx = blockIdx.x * 256 + threadIdx.x;  // 0..24575
  const int j = idx >> 12;
  const float kv = k_in[idx];
  const float ctx = newq_t[idx] + b_lin[j];
  float v = kv * kv + 2.f * kv + ctx * (1.f + fabsf(kv));
  v = fminf(fmaxf(v, 0.f), 6.f);
  k_mod[idx] = v;
}

// ---------------- out[n][j] = (sum_m q[n,m]*k_mod[j,m]) / 64 ----------------
__global__ __launch_bounds__(256) void dot_kernel(const ushort* __restrict__ q,
                                                  const float* __restrict__ k_mod,
                                                  float* __restrict__ out) {
  const int wave = threadIdx.x >> 6, lane = threadIdx.x & 63;
  const int n = blockIdx.x * 4 + wave;  // grid 1024
  const uint4* Q = (const uint4*)(q + (size_t)n * NDIM);  // 512 x 16B (8 bf16)
  float acc[6] = {0.f, 0.f, 0.f, 0.f, 0.f, 0.f};
  for (int it = lane; it < 512; it += 64) {
    uint4 v = Q[it];
    float qf[8];
    qf[0] = __builtin_bit_cast(float, v.x << 16);
    qf[1] = __builtin_bit_cast(float, v.x & 0xffff0000u);
    qf[2] = __builtin_bit_cast(float, v.y << 16);
    qf[3] = __builtin_bit_cast(float, v.y & 0xffff0000u);
    qf[4] = __builtin_bit_cast(float, v.z << 16);
    qf[5] = __builtin_bit_cast(float, v.z & 0xffff0000u);
    qf[6] = __builtin_bit_cast(float, v.w << 16);
    qf[7] = __builtin_bit_cast(float, v.w & 0xffff0000u);
#pragma unroll
    for (int j = 0; j < 6; ++j) {
      const float4* KM = (const float4*)(k_mod + j * NDIM);
      float4 k0 = KM[it * 2], k1 = KM[it * 2 + 1];
      acc[j] += qf[0] * k0.x + qf[1] * k0.y + qf[2] * k0.z + qf[3] * k0.w
              + qf[4] * k1.x + qf[5] * k1.y + qf[6] * k1.z + qf[7] * k1.w;
    }
  }
#pragma unroll
  for (int j = 0; j < 6; ++j)
#pragma unroll
    for (int off = 1; off < 64; off <<= 1) acc[j] += __shfl_xor(acc[j], off);
  if (lane == 0) {
#pragma unroll
    for (int j = 0; j < 6; ++j) out[n * 6 + j] = acc[j] * 0.015625f;  // /sqrt(4096)
  }
}

extern "C" void kernel_launch(void* const* d_in, const int* in_sizes, int n_in,
                              void* d_out, int out_size, void* d_ws, size_t ws_size,
                              hipStream_t stream) {
  const float* data_q = (const float*)d_in[0];
  const float* data_k = (const float*)d_in[1];
  const float* W_q    = (const float*)d_in[2];
  const float* b_q    = (const float*)d_in[3];
  const float* W_lin  = (const float*)d_in[4];
  const float* b_lin  = (const float*)d_in[5];
  const float* W_k    = (const float*)d_in[6];
  const float* b_k    = (const float*)d_in[7];
  float* out = (float*)d_out;

  char* ws = (char*)d_ws;
  ushort* Abf   = (ushort*)ws;                          // 32 MB
  ushort* Bbf   = (ushort*)(ws + ((size_t)32 << 20));   // 32 MB
  ushort* q_bf  = (ushort*)(ws + ((size_t)64 << 20));   // 32 MB (bf16 q)
  float*  k_arr = (float*)(ws + ((size_t)96 << 20));    // 96 KB
  float*  newq  = k_arr + 6 * NDIM;                     // 96 KB
  float*  kmod  = newq + 6 * NDIM;                      // 96 KB

  hipMemsetAsync(newq, 0, 6 * NDIM * sizeof(float), stream);

  convert2_kernel<<<32768, 256, 0, stream>>>(data_q, Abf, W_q, Bbf);
  gemm_q_kernel<<<256, 512, 0, stream>>>(Abf, Bbf, b_q, q_bf);
  gemv_k_kernel<<<1024, 256, 0, stream>>>(data_k, W_k, b_k, k_arr);
  newq_kernel<<<dim3(16, 32), 256, 0, stream>>>(q_bf, W_lin, newq);
  kmod_kernel<<<96, 256, 0, stream>>>(k_arr, newq, b_lin, kmod);
  dot_kernel<<<1024, 256, 0, stream>>>(q_bf, kmod, out);
}